// Round 5
// baseline (333.537 us; speedup 1.0000x reference)
//
#include <hip/hip_runtime.h>
#include <hip/hip_bf16.h>

// B=128, T=512, D_IN=512, D_OUT=512
// currents[M=65536][512] = X[M][512] . W[512][512]^T + bias ; then LIF scan over T.
#define M_TOT 65536
#define K_DIM 512
#define N_DIM 512
#define T_STEPS 512
#define BETA 0.95f

#define BM 128
#define BN 128
#define BK 64

typedef __attribute__((ext_vector_type(8))) short bf16x8;
typedef __attribute__((ext_vector_type(4))) float f32x4;

static __device__ __forceinline__ unsigned short f2bf(float f) {
    __hip_bfloat16 h = __float2bfloat16(f);   // compiler emits v_cvt_pk_bf16_f32
    return __builtin_bit_cast(unsigned short, h);
}

// cvt + swizzled LDS write of one K-step's staged registers (same swizzle as
// the verified round-4 kernel: 8B-group g' = g ^ 2*(row&7) at ushort granularity)
static __device__ __forceinline__ void stage_tiles(
    unsigned short (*__restrict__ Xs)[BK], unsigned short (*__restrict__ Ws)[BK],
    const float4* xr, const float4* wv, int sr0, int skg)
{
    #pragma unroll
    for (int i = 0; i < 8; ++i) {
        int r   = sr0 + i * 16;
        int kgs = skg ^ ((r & 7) << 3);
        ushort4 xb, wb;
        xb.x = f2bf(xr[i].x); xb.y = f2bf(xr[i].y); xb.z = f2bf(xr[i].z); xb.w = f2bf(xr[i].w);
        wb.x = f2bf(wv[i].x); wb.y = f2bf(wv[i].y); wb.z = f2bf(wv[i].z); wb.w = f2bf(wv[i].w);
        *(ushort4*)(&Xs[r][kgs]) = xb;
        *(ushort4*)(&Ws[r][kgs]) = wb;
    }
}

__global__ __launch_bounds__(256, 2) void gemm_currents(
    const float* __restrict__ X,   // [M_TOT][K_DIM]
    const float* __restrict__ W,   // [N_DIM][K_DIM]
    const float* __restrict__ bias,// [N_DIM]
    float* __restrict__ C,         // [M_TOT][N_DIM]
    float* __restrict__ sum_out)   // zeroed here (consumed by lif_scan later)
{
    // double-buffered bf16 tiles: 2 x (16+16) KB = 64 KB
    __shared__ unsigned short Xs[2][BM][BK];
    __shared__ unsigned short Ws[2][BN][BK];

    // XCD-bijective swizzle (2048 % 8 == 0): 4 n-tiles of an m-tile share an XCD L2.
    const int lin  = blockIdx.x;            // 0..2047
    const int swz  = (lin & 7) * 256 + (lin >> 3);
    const int mtile = swz >> 2;
    const int ntile = swz & 3;

    const int tid  = threadIdx.x;
    const int lane = tid & 63;
    const int wave = tid >> 6;
    const int wr = wave >> 1;
    const int wc = wave & 1;

    if (lin == 0 && tid == 0) *sum_out = 0.0f;

    const int row0 = mtile * BM;
    const int col0 = ntile * BN;

    f32x4 acc[4][4] = {};

    // staging geometry: 128 rows x 16 float4-groups, 8 per thread
    const int sr0 = tid >> 4;
    const int skg = (tid & 15) << 2;
    const float* xbase = X + (size_t)row0 * K_DIM + skg;
    const float* wbase = W + (size_t)col0 * K_DIM + skg;

    float4 xr[8], wv[8];

    // ---- prologue: load + stage K-step 0
    #pragma unroll
    for (int i = 0; i < 8; ++i) {
        int r = sr0 + i * 16;
        xr[i] = *(const float4*)(xbase + (size_t)r * K_DIM);
        wv[i] = *(const float4*)(wbase + (size_t)r * K_DIM);
    }
    stage_tiles(Xs[0], Ws[0], xr, wv, sr0, skg);

    const int frow = lane & 15;
    const int cblk = lane >> 4;

    for (int t = 0; t < 8; ++t) {
        __syncthreads();          // buf[t&1] fully staged; prev reads of buf[t^1] done

        // ---- issue next K-step's global loads (in flight during the MFMAs)
        if (t < 7) {
            const int k0n = (t + 1) * BK;
            #pragma unroll
            for (int i = 0; i < 8; ++i) {
                int r = sr0 + i * 16;
                xr[i] = *(const float4*)(xbase + (size_t)r * K_DIM + k0n);
                wv[i] = *(const float4*)(wbase + (size_t)r * K_DIM + k0n);
            }
        }

        // ---- compute from buf[t&1]
        unsigned short (*Xb)[BK] = Xs[t & 1];
        unsigned short (*Wb)[BK] = Ws[t & 1];
        #pragma unroll
        for (int kh = 0; kh < 2; ++kh) {
            bf16x8 afr[4], bfr[4];
            #pragma unroll
            for (int m = 0; m < 4; ++m) {
                int row = wr * 64 + m * 16 + frow;
                int c = (kh * 4 + cblk) ^ (row & 7);
                afr[m] = *(const bf16x8*)(&Xb[row][c * 8]);
            }
            #pragma unroll
            for (int n = 0; n < 4; ++n) {
                int row = wc * 64 + n * 16 + frow;
                int c = (kh * 4 + cblk) ^ (row & 7);
                bfr[n] = *(const bf16x8*)(&Wb[row][c * 8]);
            }
            #pragma unroll
            for (int m = 0; m < 4; ++m)
                #pragma unroll
                for (int n = 0; n < 4; ++n)
                    acc[m][n] = __builtin_amdgcn_mfma_f32_16x16x32_bf16(
                        afr[m], bfr[n], acc[m][n], 0, 0, 0);
        }

        // ---- convert + stage into the other buffer (after compute: no hazard)
        if (t < 7)
            stage_tiles(Xs[(t + 1) & 1], Ws[(t + 1) & 1], xr, wv, sr0, skg);
    }

    // epilogue: C/D layout col=lane&15, row=(lane>>4)*4+reg
    const int crow_base = (lane >> 4) * 4;
    const int ccol = lane & 15;
    #pragma unroll
    for (int n = 0; n < 4; ++n) {
        int col = col0 + wc * 64 + n * 16 + ccol;
        float bv = bias[col];
        #pragma unroll
        for (int m = 0; m < 4; ++m) {
            int rowb = row0 + wr * 64 + m * 16 + crow_base;
            #pragma unroll
            for (int r = 0; r < 4; ++r) {
                C[(size_t)(rowb + r) * N_DIM + col] = acc[m][n][r] + bv;
            }
        }
    }
}

// One thread per neuron chain (b,d). 16-deep two-buffer register pipeline;
// plain loads (currents are L3-resident right after the GEMM), NT stores.
__global__ __launch_bounds__(256) void lif_scan(
    float* __restrict__ C,        // [B][T][D] currents in, spikes out (in place)
    float* __restrict__ sum_out)
{
    const int idx = blockIdx.x * 256 + threadIdx.x;  // 0..65535
    float* p = C + (size_t)(idx >> 9) * (T_STEPS * N_DIM) + (idx & 511);

    float mem = 0.0f;
    int count = 0;
    float a[16], b[16];

    #pragma unroll
    for (int j = 0; j < 16; ++j)
        a[j] = p[(size_t)j * N_DIM];

    for (int t = 0; t < T_STEPS; t += 32) {
        #pragma unroll
        for (int j = 0; j < 16; ++j)
            b[j] = p[(size_t)(t + 16 + j) * N_DIM];
        #pragma unroll
        for (int j = 0; j < 16; ++j) {
            mem = BETA * mem + a[j];
            float spk = (mem > 1.0f) ? 1.0f : 0.0f;
            mem -= spk;
            __builtin_nontemporal_store(spk, p + (size_t)(t + j) * N_DIM);
            count += (int)spk;
        }
        if (t + 32 < T_STEPS) {
            #pragma unroll
            for (int j = 0; j < 16; ++j)
                a[j] = p[(size_t)(t + 32 + j) * N_DIM];
        }
        #pragma unroll
        for (int j = 0; j < 16; ++j) {
            mem = BETA * mem + b[j];
            float spk = (mem > 1.0f) ? 1.0f : 0.0f;
            mem -= spk;
            __builtin_nontemporal_store(spk, p + (size_t)(t + 16 + j) * N_DIM);
            count += (int)spk;
        }
    }

    // block-reduce spike count (exact integer arithmetic)
    #pragma unroll
    for (int off = 32; off > 0; off >>= 1)
        count += __shfl_down(count, off);
    __shared__ int wsum[4];
    if ((threadIdx.x & 63) == 0) wsum[threadIdx.x >> 6] = count;
    __syncthreads();
    if (threadIdx.x == 0) {
        int tot = wsum[0] + wsum[1] + wsum[2] + wsum[3];
        atomicAdd(sum_out, (float)tot);
    }
}

extern "C" void kernel_launch(void* const* d_in, const int* in_sizes, int n_in,
                              void* d_out, int out_size, void* d_ws, size_t ws_size,
                              hipStream_t stream) {
    const float* X    = (const float*)d_in[0];  // [128,512,512]
    const float* W    = (const float*)d_in[1];  // [512,512]
    const float* bias = (const float*)d_in[2];  // [512]
    float* out = (float*)d_out;                 // [128*512*512] spikes + [1] sum
    float* sum_slot = out + (size_t)M_TOT * N_DIM;

    gemm_currents<<<(M_TOT / BM) * (N_DIM / BN), 256, 0, stream>>>(X, W, bias, out, sum_slot);
    lif_scan<<<M_TOT / 256, 256, 0, stream>>>(out, sum_slot);
}

// Round 6
// 315.534 us; speedup vs baseline: 1.0571x; 1.0571x over previous
//
#include <hip/hip_runtime.h>
#include <hip/hip_bf16.h>

// B=128, T=512, D_IN=512, D_OUT=512
// currents[M=65536][512] = X[M][512] . W[512][512]^T + bias ; then LIF scan over T.
#define M_TOT 65536
#define K_DIM 512
#define N_DIM 512
#define T_STEPS 512
#define BETA 0.95f

#define BM 128
#define BN 128
#define BK 64

typedef __attribute__((ext_vector_type(8))) short bf16x8;
typedef __attribute__((ext_vector_type(8))) unsigned short u16x8;
typedef __attribute__((ext_vector_type(4))) float f32x4;

#define X_ELEMS ((size_t)M_TOT * K_DIM)   // 33,554,432
#define W_ELEMS ((size_t)N_DIM * K_DIM)   // 262,144
#define WS_NEEDED ((X_ELEMS + W_ELEMS) * 2)

static __device__ __forceinline__ unsigned short f2bf(float f) {
    __hip_bfloat16 h = __float2bfloat16(f);   // v_cvt_pk_bf16_f32 (RNE)
    return __builtin_bit_cast(unsigned short, h);
}

// ---------------- pass 1: f32 -> bf16 for X and W, zero the sum slot ----------
__global__ __launch_bounds__(256) void convert_bf16(
    const float* __restrict__ X, const float* __restrict__ W,
    unsigned short* __restrict__ Xb, unsigned short* __restrict__ Wb,
    float* __restrict__ sum_out)
{
    const size_t gid = (size_t)blockIdx.x * 256 + threadIdx.x;
    if (gid == 0) *sum_out = 0.0f;
    const size_t NXT = X_ELEMS / 8;          // 4,194,304 threads for X
    if (gid < NXT) {
        const float4 v0 = *(const float4*)(X + gid * 8);
        const float4 v1 = *(const float4*)(X + gid * 8 + 4);
        u16x8 o;
        o[0] = f2bf(v0.x); o[1] = f2bf(v0.y); o[2] = f2bf(v0.z); o[3] = f2bf(v0.w);
        o[4] = f2bf(v1.x); o[5] = f2bf(v1.y); o[6] = f2bf(v1.z); o[7] = f2bf(v1.w);
        *(u16x8*)(Xb + gid * 8) = o;
    } else {
        const size_t g2 = gid - NXT;         // < 32,768 threads for W
        const float4 v0 = *(const float4*)(W + g2 * 8);
        const float4 v1 = *(const float4*)(W + g2 * 8 + 4);
        u16x8 o;
        o[0] = f2bf(v0.x); o[1] = f2bf(v0.y); o[2] = f2bf(v0.z); o[3] = f2bf(v0.w);
        o[4] = f2bf(v1.x); o[5] = f2bf(v1.y); o[6] = f2bf(v1.z); o[7] = f2bf(v1.w);
        *(u16x8*)(Wb + g2 * 8) = o;
    }
}

// ---------------- pass 2 (fast): m97-structure bf16 GEMM ---------------------
// global_load_lds 16B direct staging, linear LDS dest, PRE-SWIZZLED global
// source (rule #21) so reads use the 16B-block XOR swizzle: phys = logical ^ (row&7).
__global__ __launch_bounds__(256) void gemm_fast(
    const unsigned short* __restrict__ Xb,  // [M_TOT][K_DIM] bf16
    const unsigned short* __restrict__ Wb,  // [N_DIM][K_DIM] bf16
    const float* __restrict__ bias,
    float* __restrict__ C)
{
    __shared__ alignas(16) unsigned short Xs[BM][BK]; // 16 KB
    __shared__ alignas(16) unsigned short Ws[BN][BK]; // 16 KB

    const int lin  = blockIdx.x;            // 0..2047 (2048 % 8 == 0: bijective)
    const int swz  = (lin & 7) * 256 + (lin >> 3);
    const int mtile = swz >> 2;
    const int ntile = swz & 3;

    const int tid  = threadIdx.x;
    const int lane = tid & 63;
    const int wave = tid >> 6;
    const int wr = wave >> 1;
    const int wc = wave & 1;

    const int row0 = mtile * BM;
    const int col0 = ntile * BN;

    f32x4 acc[4][4] = {};

    // staging: instruction (wave,j) fills LDS rows wave*32+j*8 .. +7 (1 KB).
    // HW writes ldsbase + lane*16 -> lane covers row +(lane>>3), phys blk lane&7.
    // Source logical blk = (lane&7) ^ ((lane>>3)&7)  [row&7 == (lane>>3)&7].
    const int srow = lane >> 3;
    const int scb  = (lane & 7) ^ (srow & 7);
    const unsigned short* xsrc[4];
    const unsigned short* wsrc[4];
    #pragma unroll
    for (int j = 0; j < 4; ++j) {
        const int ra = row0 + wave * 32 + j * 8 + srow;
        const int rb = col0 + wave * 32 + j * 8 + srow;
        xsrc[j] = Xb + (size_t)ra * K_DIM + scb * 8;
        wsrc[j] = Wb + (size_t)rb * K_DIM + scb * 8;
    }

    const int frow = lane & 15;
    const int cblk = lane >> 4;

    #pragma unroll
    for (int t = 0; t < 8; ++t) {
        if (t) __syncthreads();   // previous compute done before overwrite
        #pragma unroll
        for (int j = 0; j < 4; ++j) {
            __builtin_amdgcn_global_load_lds(
                (const __attribute__((address_space(1))) unsigned int*)(const void*)(xsrc[j] + t * BK),
                (__attribute__((address_space(3))) unsigned int*)(void*)(&Xs[wave * 32 + j * 8][0]),
                16, 0, 0);
            __builtin_amdgcn_global_load_lds(
                (const __attribute__((address_space(1))) unsigned int*)(const void*)(wsrc[j] + t * BK),
                (__attribute__((address_space(3))) unsigned int*)(void*)(&Ws[wave * 32 + j * 8][0]),
                16, 0, 0);
        }
        __syncthreads();          // vmcnt(0) drained by compiler before barrier

        #pragma unroll
        for (int kh = 0; kh < 2; ++kh) {
            bf16x8 afr[4], bfr[4];
            #pragma unroll
            for (int m = 0; m < 4; ++m) {
                int row = wr * 64 + m * 16 + frow;
                int c = (kh * 4 + cblk) ^ (row & 7);
                afr[m] = *(const bf16x8*)(&Xs[row][c * 8]);
            }
            #pragma unroll
            for (int n = 0; n < 4; ++n) {
                int row = wc * 64 + n * 16 + frow;
                int c = (kh * 4 + cblk) ^ (row & 7);
                bfr[n] = *(const bf16x8*)(&Ws[row][c * 8]);
            }
            #pragma unroll
            for (int m = 0; m < 4; ++m)
                #pragma unroll
                for (int n = 0; n < 4; ++n)
                    acc[m][n] = __builtin_amdgcn_mfma_f32_16x16x32_bf16(
                        afr[m], bfr[n], acc[m][n], 0, 0, 0);
        }
    }

    // epilogue: C/D layout col=lane&15, row=(lane>>4)*4+reg
    const int crow_base = (lane >> 4) * 4;
    const int ccol = lane & 15;
    #pragma unroll
    for (int n = 0; n < 4; ++n) {
        int col = col0 + wc * 64 + n * 16 + ccol;
        float bv = bias[col];
        #pragma unroll
        for (int m = 0; m < 4; ++m) {
            int rowb = row0 + wr * 64 + m * 16 + crow_base;
            #pragma unroll
            for (int r = 0; r < 4; ++r) {
                C[(size_t)(rowb + r) * N_DIM + col] = acc[m][n][r] + bv;
            }
        }
    }
}

// ---------------- pass 2 (fallback, ws too small): round-5 kernel ------------
static __device__ __forceinline__ void stage_tiles(
    unsigned short (*__restrict__ Xs)[BK], unsigned short (*__restrict__ Ws)[BK],
    const float4* xr, const float4* wv, int sr0, int skg)
{
    #pragma unroll
    for (int i = 0; i < 8; ++i) {
        int r   = sr0 + i * 16;
        int kgs = skg ^ ((r & 7) << 3);
        ushort4 xb, wb;
        xb.x = f2bf(xr[i].x); xb.y = f2bf(xr[i].y); xb.z = f2bf(xr[i].z); xb.w = f2bf(xr[i].w);
        wb.x = f2bf(wv[i].x); wb.y = f2bf(wv[i].y); wb.z = f2bf(wv[i].z); wb.w = f2bf(wv[i].w);
        *(ushort4*)(&Xs[r][kgs]) = xb;
        *(ushort4*)(&Ws[r][kgs]) = wb;
    }
}

__global__ __launch_bounds__(256, 2) void gemm_slow(
    const float* __restrict__ X, const float* __restrict__ W,
    const float* __restrict__ bias, float* __restrict__ C,
    float* __restrict__ sum_out)
{
    __shared__ unsigned short Xs[2][BM][BK];
    __shared__ unsigned short Ws[2][BN][BK];

    const int lin  = blockIdx.x;
    const int swz  = (lin & 7) * 256 + (lin >> 3);
    const int mtile = swz >> 2;
    const int ntile = swz & 3;

    const int tid  = threadIdx.x;
    const int lane = tid & 63;
    const int wave = tid >> 6;
    const int wr = wave >> 1;
    const int wc = wave & 1;

    if (lin == 0 && tid == 0) *sum_out = 0.0f;

    const int row0 = mtile * BM;
    const int col0 = ntile * BN;

    f32x4 acc[4][4] = {};

    const int sr0 = tid >> 4;
    const int skg = (tid & 15) << 2;
    const float* xbase = X + (size_t)row0 * K_DIM + skg;
    const float* wbase = W + (size_t)col0 * K_DIM + skg;

    float4 xr[8], wv[8];
    #pragma unroll
    for (int i = 0; i < 8; ++i) {
        int r = sr0 + i * 16;
        xr[i] = *(const float4*)(xbase + (size_t)r * K_DIM);
        wv[i] = *(const float4*)(wbase + (size_t)r * K_DIM);
    }
    stage_tiles(Xs[0], Ws[0], xr, wv, sr0, skg);

    const int frow = lane & 15;
    const int cblk = lane >> 4;

    for (int t = 0; t < 8; ++t) {
        __syncthreads();
        if (t < 7) {
            const int k0n = (t + 1) * BK;
            #pragma unroll
            for (int i = 0; i < 8; ++i) {
                int r = sr0 + i * 16;
                xr[i] = *(const float4*)(xbase + (size_t)r * K_DIM + k0n);
                wv[i] = *(const float4*)(wbase + (size_t)r * K_DIM + k0n);
            }
        }
        unsigned short (*Xb)[BK] = Xs[t & 1];
        unsigned short (*Wb)[BK] = Ws[t & 1];
        #pragma unroll
        for (int kh = 0; kh < 2; ++kh) {
            bf16x8 afr[4], bfr[4];
            #pragma unroll
            for (int m = 0; m < 4; ++m) {
                int row = wr * 64 + m * 16 + frow;
                int c = (kh * 4 + cblk) ^ (row & 7);
                afr[m] = *(const bf16x8*)(&Xb[row][c * 8]);
            }
            #pragma unroll
            for (int n = 0; n < 4; ++n) {
                int row = wc * 64 + n * 16 + frow;
                int c = (kh * 4 + cblk) ^ (row & 7);
                bfr[n] = *(const bf16x8*)(&Wb[row][c * 8]);
            }
            #pragma unroll
            for (int m = 0; m < 4; ++m)
                #pragma unroll
                for (int n = 0; n < 4; ++n)
                    acc[m][n] = __builtin_amdgcn_mfma_f32_16x16x32_bf16(
                        afr[m], bfr[n], acc[m][n], 0, 0, 0);
        }
        if (t < 7)
            stage_tiles(Xs[(t + 1) & 1], Ws[(t + 1) & 1], xr, wv, sr0, skg);
    }

    const int crow_base = (lane >> 4) * 4;
    const int ccol = lane & 15;
    #pragma unroll
    for (int n = 0; n < 4; ++n) {
        int col = col0 + wc * 64 + n * 16 + ccol;
        float bv = bias[col];
        #pragma unroll
        for (int m = 0; m < 4; ++m) {
            int rowb = row0 + wr * 64 + m * 16 + crow_base;
            #pragma unroll
            for (int r = 0; r < 4; ++r) {
                C[(size_t)(rowb + r) * N_DIM + col] = acc[m][n][r] + bv;
            }
        }
    }
}

// ---------------- pass 3: LIF scan, depth-32 register pipeline ---------------
__global__ __launch_bounds__(256) void lif_scan(
    float* __restrict__ C,        // [B][T][D] currents in, spikes out (in place)
    float* __restrict__ sum_out)
{
    const int idx = blockIdx.x * 256 + threadIdx.x;  // 0..65535
    float* p = C + (size_t)(idx >> 9) * (T_STEPS * N_DIM) + (idx & 511);

    float mem = 0.0f;
    int count = 0;
    float a[32], b[32];

    #pragma unroll
    for (int j = 0; j < 32; ++j)
        a[j] = p[(size_t)j * N_DIM];

    for (int t = 0; t < T_STEPS; t += 64) {
        #pragma unroll
        for (int j = 0; j < 32; ++j)
            b[j] = p[(size_t)(t + 32 + j) * N_DIM];
        #pragma unroll
        for (int j = 0; j < 32; ++j) {
            mem = BETA * mem + a[j];
            float spk = (mem > 1.0f) ? 1.0f : 0.0f;
            mem -= spk;
            __builtin_nontemporal_store(spk, p + (size_t)(t + j) * N_DIM);
            count += (int)spk;
        }
        if (t + 64 < T_STEPS) {
            #pragma unroll
            for (int j = 0; j < 32; ++j)
                a[j] = p[(size_t)(t + 64 + j) * N_DIM];
        }
        #pragma unroll
        for (int j = 0; j < 32; ++j) {
            mem = BETA * mem + b[j];
            float spk = (mem > 1.0f) ? 1.0f : 0.0f;
            mem -= spk;
            __builtin_nontemporal_store(spk, p + (size_t)(t + 32 + j) * N_DIM);
            count += (int)spk;
        }
    }

    #pragma unroll
    for (int off = 32; off > 0; off >>= 1)
        count += __shfl_down(count, off);
    __shared__ int wsum[4];
    if ((threadIdx.x & 63) == 0) wsum[threadIdx.x >> 6] = count;
    __syncthreads();
    if (threadIdx.x == 0) {
        int tot = wsum[0] + wsum[1] + wsum[2] + wsum[3];
        atomicAdd(sum_out, (float)tot);
    }
}

extern "C" void kernel_launch(void* const* d_in, const int* in_sizes, int n_in,
                              void* d_out, int out_size, void* d_ws, size_t ws_size,
                              hipStream_t stream) {
    const float* X    = (const float*)d_in[0];  // [128,512,512]
    const float* W    = (const float*)d_in[1];  // [512,512]
    const float* bias = (const float*)d_in[2];  // [512]
    float* out = (float*)d_out;                 // [128*512*512] spikes + [1] sum
    float* sum_slot = out + (size_t)M_TOT * N_DIM;

    if (ws_size >= WS_NEEDED) {
        unsigned short* Xb = (unsigned short*)d_ws;
        unsigned short* Wb = Xb + X_ELEMS;
        const int nconv = (int)((X_ELEMS / 8 + W_ELEMS / 8) / 256);  // 16512
        convert_bf16<<<nconv, 256, 0, stream>>>(X, W, Xb, Wb, sum_slot);
        gemm_fast<<<(M_TOT / BM) * (N_DIM / BN), 256, 0, stream>>>(Xb, Wb, bias, out);
    } else {
        gemm_slow<<<(M_TOT / BM) * (N_DIM / BN), 256, 0, stream>>>(X, W, bias, out, sum_slot);
    }
    lif_scan<<<M_TOT / 256, 256, 0, stream>>>(out, sum_slot);
}